// Round 1
// baseline (230.293 us; speedup 1.0000x reference)
//
#include <hip/hip_runtime.h>

// CASREL loss, B=32,S=512,H=1024,R=64 -> scalar fp32 loss.
// v2: barrier-free streaming MFMA. Fragments (A from ctx fp32->bf16, B from
// prepacked WtG bf16) are loaded DIRECTLY from global per 32x32x16 MFMA tile;
// no LDS staging, no per-K-step barriers. K split 4 ways across the block's
// waves (one LDS reduction at the end). Finalize fused via last-block counter.

#define B_  32
#define S_  512
#define H_  1024
#define R_  64
#define M_  (B_ * S_)      // 16384 rows
#define NPAD 160           // 130 valid cols padded to 5*32
#define NVALID 130
#define KW  256            // K-range per wave (H_/4)

typedef __attribute__((ext_vector_type(4)))  float floatx4;
typedef __attribute__((ext_vector_type(16))) float floatx16;
typedef __attribute__((ext_vector_type(8)))  short short8;     // 8 bf16 (4 VGPRs)

__device__ __forceinline__ unsigned short f2bf(float f) {
    unsigned int u = __float_as_uint(f);
    u = (u + 0x7FFFu + ((u >> 16) & 1u)) >> 16;   // RNE
    return (unsigned short)u;
}

__device__ __forceinline__ short8 cvt8(float4 a, float4 b) {
    union { unsigned short us[8]; short8 s8; } u;
    u.us[0] = f2bf(a.x); u.us[1] = f2bf(a.y); u.us[2] = f2bf(a.z); u.us[3] = f2bf(a.w);
    u.us[4] = f2bf(b.x); u.us[5] = f2bf(b.y); u.us[6] = f2bf(b.z); u.us[7] = f2bf(b.w);
    return u.s8;
}

// ---- K1 (merged): blocks [0,NPAD) build WtG; blocks [NPAD,NPAD+B_) do subj ----
// WtG col n: 0..63 = Wo_h[:,n], 64..127 = Wo_t[:,n-64], 128 = Ws_h, 129 = Ws_t, else 0
__global__ __launch_bounds__(256) void aux_kernel(
        const float* __restrict__ ctx, const float* __restrict__ head,
        const float* __restrict__ tail, const float* __restrict__ masks,
        const float* __restrict__ Wo_h, const float* __restrict__ Wo_t,
        const float* __restrict__ Ws_h, const float* __restrict__ Ws_t,
        const float* __restrict__ bo_h, const float* __restrict__ bo_t,
        const float* __restrict__ bs_h, const float* __restrict__ bs_t,
        unsigned short* __restrict__ WtG, float* __restrict__ rowBias,
        float* __restrict__ accum) {
    const int tid = threadIdx.x;
    __shared__ float subj[H_];
    __shared__ float part[256];
    __shared__ int cnt;
    __shared__ int   sidx[8];
    __shared__ float sw[8];

    if (blockIdx.x < NPAD) {
        const int n = blockIdx.x;
        for (int k = tid; k < H_; k += 256) {
            float v;
            if (n < 64)        v = Wo_h[k * R_ + n];
            else if (n < 128)  v = Wo_t[k * R_ + (n - 64)];
            else if (n == 128) v = Ws_h[k];
            else if (n == 129) v = Ws_t[k];
            else               v = 0.0f;
            WtG[n * H_ + k] = f2bf(v);
        }
        return;
    }

    const int b = blockIdx.x - NPAD;
    if (tid == 0) cnt = 0;
    __syncthreads();
    float msk = 0.0f;
    for (int s = tid; s < S_; s += 256) {
        float w = 0.5f * (head[b * S_ + s] + tail[b * S_ + s]);
        if (w != 0.0f) {
            int i = atomicAdd(&cnt, 1);
            if (i < 8) { sidx[i] = s; sw[i] = w; }
        }
        msk += masks[b * S_ + s];
    }
    for (int o = 32; o > 0; o >>= 1) msk += __shfl_down(msk, o, 64);
    if ((tid & 63) == 0) atomicAdd(&accum[1], msk);
    __syncthreads();
    const int nnz = cnt < 8 ? cnt : 8;
    for (int h = tid; h < H_; h += 256) {
        float a = 0.0f;
        for (int i = 0; i < nnz; i++)
            a += sw[i] * ctx[((size_t)b * S_ + sidx[i]) * H_ + h];
        subj[h] = a;
    }
    __syncthreads();
    // subject @ W for object columns, 2-way k-split across the 256 threads
    {
        const int c = tid & 127, half = tid >> 7;
        const float* W = (c < 64) ? Wo_h : Wo_t;
        const int cc = c & 63;
        float a2 = 0.0f;
        const int k0 = half * 512;
        for (int k = k0; k < k0 + 512; ++k) a2 += subj[k] * W[k * R_ + cc];
        part[tid] = a2;
    }
    __syncthreads();
    if (tid < NPAD) {
        float bias = tid < 64  ? bo_h[tid]
                   : tid < 128 ? bo_t[tid - 64]
                   : tid == 128 ? bs_h[0]
                   : tid == 129 ? bs_t[0] : 0.0f;
        float a2 = (tid < 128) ? (part[tid] + part[tid + 128]) : 0.0f;
        rowBias[b * NPAD + tid] = bias + a2;
    }
}

// ---- K2: barrier-free streaming MFMA + BCE + masked reduction + finalize ----
// Block = 4 waves, one 32-row slab. Wave w: K in [w*256, w*256+256).
// 5 col-tiles of 32 (NPAD=160). mfma_f32_32x32x16_bf16:
//   A frag: lane l -> row l&31,  k = (l>>5)*8 + j   (8 contiguous k)
//   B frag: lane l -> col l&31,  k = (l>>5)*8 + j   (WtG is [n][k], k contiguous)
//   C frag: col = lane&31, row = (reg&3) + 8*(reg>>2) + 4*(lane>>5)   [m74/m101]
__global__ __launch_bounds__(256, 2) void main_kernel(
        const float* __restrict__ ctx, const unsigned short* __restrict__ WtG,
        const float* __restrict__ rowBias, const float* __restrict__ masks,
        const float* __restrict__ ash, const float* __restrict__ ast,
        const float* __restrict__ oh, const float* __restrict__ ot,
        float* __restrict__ accum, float* __restrict__ out) {
    __shared__ float red[3 * 5 * 16 * 64];   // 60 KB: partial accs of waves 1..3

    const int tid  = threadIdx.x;
    const int wave = tid >> 6, lane = tid & 63;
    const int r31  = lane & 31, q = lane >> 5;      // q in {0,1}
    const int gm0  = blockIdx.x * 32;               // 32 rows per block
    const int b    = gm0 >> 9;                      // 512 rows per batch

    const float*          aP = ctx + (size_t)(gm0 + r31) * H_ + wave * KW + q * 8;
    const unsigned short* bP = WtG + (size_t)r31 * H_ + wave * KW + q * 8;

    floatx16 acc[5];
#pragma unroll
    for (int t = 0; t < 5; ++t)
#pragma unroll
        for (int r = 0; r < 16; ++r) acc[t][r] = 0.0f;

    // prologue: k-step 0 in regs
    float4 a0 = *(const float4*)(aP);
    float4 a1 = *(const float4*)(aP + 4);
    short8 bc[5];
#pragma unroll
    for (int t = 0; t < 5; ++t) bc[t] = *(const short8*)(bP + t * 32 * H_);

    // 16 k-steps of 16; prefetch next step while issuing MFMAs (no barriers)
#pragma unroll
    for (int ks = 0; ks < 15; ++ks) {
        float4 na0 = *(const float4*)(aP + (ks + 1) * 16);
        float4 na1 = *(const float4*)(aP + (ks + 1) * 16 + 4);
        short8 nb[5];
#pragma unroll
        for (int t = 0; t < 5; ++t)
            nb[t] = *(const short8*)(bP + t * 32 * H_ + (ks + 1) * 16);
        const short8 af = cvt8(a0, a1);
#pragma unroll
        for (int t = 0; t < 5; ++t)
            acc[t] = __builtin_amdgcn_mfma_f32_32x32x16_bf16(af, bc[t], acc[t], 0, 0, 0);
        a0 = na0; a1 = na1;
#pragma unroll
        for (int t = 0; t < 5; ++t) bc[t] = nb[t];
    }
    {
        const short8 af = cvt8(a0, a1);
#pragma unroll
        for (int t = 0; t < 5; ++t)
            acc[t] = __builtin_amdgcn_mfma_f32_32x32x16_bf16(af, bc[t], acc[t], 0, 0, 0);
    }

    // K-split reduction: waves 1..3 dump partials, wave 0 sums (conflict-free)
    if (wave > 0) {
        float* dst = &red[(wave - 1) * 5120];
#pragma unroll
        for (int t = 0; t < 5; ++t)
#pragma unroll
            for (int r = 0; r < 16; ++r)
                dst[(t * 16 + r) * 64 + lane] = acc[t][r];
    }
    __syncthreads();
    if (wave == 0) {
#pragma unroll
        for (int t = 0; t < 5; ++t)
#pragma unroll
            for (int r = 0; r < 16; ++r) {
                const int o = (t * 16 + r) * 64 + lane;
                acc[t][r] += red[o] + red[o + 5120] + red[o + 10240];
            }

        // epilogue: logits -> BCE * mask -> sum
        float lsum = 0.0f;
#pragma unroll
        for (int t = 0; t < 5; ++t) {
            const int col = t * 32 + r31;
            const float rb = rowBias[b * NPAD + col];
#pragma unroll
            for (int r = 0; r < 16; ++r) {
                const int row = gm0 + (r & 3) + 8 * (r >> 2) + 4 * q;
                const float l = acc[t][r] + rb;
                float tgt;
                bool valid = true;
                if (col < 64)        tgt = oh[(size_t)row * R_ + col];
                else if (col < 128)  tgt = ot[(size_t)row * R_ + (col - 64)];
                else if (col == 128) tgt = ash[row];
                else if (col == 129) tgt = ast[row];
                else                 valid = false;
                if (valid) {
                    const float mk = masks[row];
                    const float bce = fmaxf(l, 0.0f) - l * tgt + log1pf(__expf(-fabsf(l)));
                    lsum += bce * mk;
                }
            }
        }
#pragma unroll
        for (int o = 32; o > 0; o >>= 1) lsum += __shfl_down(lsum, o, 64);
        if (lane == 0) {
            atomicAdd(&accum[0], lsum);
            __threadfence();
            const unsigned int prev = atomicAdd((unsigned int*)(accum + 2), 1u);
            if (prev == gridDim.x - 1) {         // last block finalizes
                const float s = atomicAdd(&accum[0], 0.0f);
                const float m = atomicAdd(&accum[1], 0.0f);
                out[0] = s / m;
            }
        }
    }
}

extern "C" void kernel_launch(void* const* d_in, const int* in_sizes, int n_in,
                              void* d_out, int out_size, void* d_ws, size_t ws_size,
                              hipStream_t stream) {
    const float* ctx   = (const float*)d_in[0];
    const float* masks = (const float*)d_in[1];
    const float* ash   = (const float*)d_in[2];
    const float* ast   = (const float*)d_in[3];
    const float* sh    = (const float*)d_in[4];
    const float* st    = (const float*)d_in[5];
    const float* oh    = (const float*)d_in[6];
    const float* ot    = (const float*)d_in[7];
    const float* Ws_h  = (const float*)d_in[8];
    const float* bs_h  = (const float*)d_in[9];
    const float* Ws_t  = (const float*)d_in[10];
    const float* bs_t  = (const float*)d_in[11];
    const float* Wo_h  = (const float*)d_in[12];
    const float* bo_h  = (const float*)d_in[13];
    const float* Wo_t  = (const float*)d_in[14];
    const float* bo_t  = (const float*)d_in[15];
    float* out = (float*)d_out;

    char* ws = (char*)d_ws;
    float* accum   = (float*)(ws + 0);                 // [0]=loss, [1]=msum, [2]=block counter
    float* rowBias = (float*)(ws + 256);               // [32][160] fp32
    unsigned short* WtG = (unsigned short*)(ws + 256 + 32 * NPAD * 4); // [160][1024] bf16

    hipMemsetAsync(accum, 0, 12, stream);
    aux_kernel<<<NPAD + B_, 256, 0, stream>>>(ctx, sh, st, masks, Wo_h, Wo_t,
                                              Ws_h, Ws_t, bo_h, bo_t, bs_h, bs_t,
                                              WtG, rowBias, accum);
    main_kernel<<<M_ / 32, 256, 0, stream>>>(ctx, WtG, rowBias, masks,
                                             ash, ast, oh, ot, accum, out);
}

// Round 2
// 212.002 us; speedup vs baseline: 1.0863x; 1.0863x over previous
//
#include <hip/hip_runtime.h>

// CASREL loss, B=32,S=512,H=1024,R=64 -> scalar fp32 loss.
// v3: v1 compute structure (MT=32, 4 waves, 16x16x32 MFMA, 20-VGPR acc/wave)
// + double-buffered LDS with global_load_lds(16B) for B (source-XOR swizzled,
// linear LDS dest) and split-issue reg-staged A (loads before MFMA phase,
// cvt+ds_write after). One barrier per K-chunk; loads overlap compute.

#define B_  32
#define S_  512
#define H_  1024
#define R_  64
#define M_  (B_ * S_)      // 16384 rows
#define NPAD 160           // 130 valid cols padded
#define NVALID 130
#define BK 64
#define BKP 72             // A LDS pad (2-way conflicts = free)
#define MT 32              // rows per block
#define NCHUNK (H_ / BK)   // 16

typedef __attribute__((ext_vector_type(4))) float  floatx4;
typedef __attribute__((ext_vector_type(8))) short  short8;     // 8 bf16
typedef __attribute__((ext_vector_type(4))) unsigned short u16x4;

__device__ __forceinline__ unsigned short f2bf(float f) {
    unsigned int u = __float_as_uint(f);
    u = (u + 0x7FFFu + ((u >> 16) & 1u)) >> 16;   // RNE
    return (unsigned short)u;
}

__device__ __forceinline__ void gload_lds16(const unsigned short* g, unsigned short* l) {
    __builtin_amdgcn_global_load_lds(
        (const __attribute__((address_space(1))) unsigned int*)g,
        (__attribute__((address_space(3))) unsigned int*)l, 16, 0, 0);
}

// ---- K1 (merged): blocks [0,NPAD) build WtG; blocks [NPAD,NPAD+B_) do subj ----
__global__ __launch_bounds__(256) void aux_kernel(
        const float* __restrict__ ctx, const float* __restrict__ head,
        const float* __restrict__ tail, const float* __restrict__ masks,
        const float* __restrict__ Wo_h, const float* __restrict__ Wo_t,
        const float* __restrict__ Ws_h, const float* __restrict__ Ws_t,
        const float* __restrict__ bo_h, const float* __restrict__ bo_t,
        const float* __restrict__ bs_h, const float* __restrict__ bs_t,
        unsigned short* __restrict__ WtG, float* __restrict__ rowBias,
        float* __restrict__ accum) {
    const int tid = threadIdx.x;
    __shared__ float subj[H_];
    __shared__ float part[256];
    __shared__ int cnt;
    __shared__ int   sidx[8];
    __shared__ float sw[8];

    if (blockIdx.x < NPAD) {
        const int n = blockIdx.x;
        for (int k = tid; k < H_; k += 256) {
            float v;
            if (n < 64)        v = Wo_h[k * R_ + n];
            else if (n < 128)  v = Wo_t[k * R_ + (n - 64)];
            else if (n == 128) v = Ws_h[k];
            else if (n == 129) v = Ws_t[k];
            else               v = 0.0f;
            WtG[n * H_ + k] = f2bf(v);
        }
        return;
    }

    const int b = blockIdx.x - NPAD;
    if (tid == 0) cnt = 0;
    __syncthreads();
    float msk = 0.0f;
    for (int s = tid; s < S_; s += 256) {
        float w = 0.5f * (head[b * S_ + s] + tail[b * S_ + s]);
        if (w != 0.0f) {
            int i = atomicAdd(&cnt, 1);
            if (i < 8) { sidx[i] = s; sw[i] = w; }
        }
        msk += masks[b * S_ + s];
    }
    for (int o = 32; o > 0; o >>= 1) msk += __shfl_down(msk, o, 64);
    if ((tid & 63) == 0) atomicAdd(&accum[1], msk);
    __syncthreads();
    const int nnz = cnt < 8 ? cnt : 8;
    for (int h = tid; h < H_; h += 256) {
        float a = 0.0f;
        for (int i = 0; i < nnz; i++)
            a += sw[i] * ctx[((size_t)b * S_ + sidx[i]) * H_ + h];
        subj[h] = a;
    }
    __syncthreads();
    {   // subject @ W for object columns, 2-way k-split
        const int c = tid & 127, half = tid >> 7;
        const float* W = (c < 64) ? Wo_h : Wo_t;
        const int cc = c & 63;
        float a2 = 0.0f;
        const int k0 = half * 512;
        for (int k = k0; k < k0 + 512; ++k) a2 += subj[k] * W[k * R_ + cc];
        part[tid] = a2;
    }
    __syncthreads();
    if (tid < NPAD) {
        float bias = tid < 64  ? bo_h[tid]
                   : tid < 128 ? bo_t[tid - 64]
                   : tid == 128 ? bs_h[0]
                   : tid == 129 ? bs_t[0] : 0.0f;
        float a2 = (tid < 128) ? (part[tid] + part[tid + 128]) : 0.0f;
        rowBias[b * NPAD + tid] = bias + a2;
    }
}

// ---- K2: double-buffered pipelined GEMM + BCE + masked reduction + finalize ----
__global__ __launch_bounds__(256, 2) void main_kernel(
        const float* __restrict__ ctx, const unsigned short* __restrict__ WtG,
        const float* __restrict__ rowBias, const float* __restrict__ masks,
        const float* __restrict__ ash, const float* __restrict__ ast,
        const float* __restrict__ oh, const float* __restrict__ ot,
        float* __restrict__ accum, float* __restrict__ out) {
    __shared__ __align__(16) unsigned short Asm[2][MT * BKP];    // 9.2 KB
    __shared__ __align__(16) unsigned short Bsm[2][NPAD * BK];   // 41 KB
    __shared__ float rbuf[4];

    const int tid  = threadIdx.x;
    const int gm0  = blockIdx.x * MT;
    const int b    = gm0 >> 9;
    const int wave = tid >> 6, lane = tid & 63;
    const int wm = wave & 1;            // row half (16 rows)
    const int wn = wave >> 1;           // col half (80 cols = 5 tiles)
    const int lr = lane & 15, q = lane >> 4;   // q in 0..3

    // A staging map: rows ar, ar+16; 16B (4 floats) per thread per row
    const int ar = tid >> 4, af = tid & 15;
    const float* aSrc = ctx + (size_t)(gm0 + ar) * H_ + af * 4;
    unsigned short* aD0 = &Asm[0][ar * BKP + af * 4];
    unsigned short* aD1 = &Asm[1][ar * BKP + af * 4];

    // B staging map (global_load_lds, linear LDS dest, source XOR-swizzled):
    // pass p: r = p*32 + (tid>>3), c = (tid&7)*16 bytes; src byte = c ^ ((r&7)<<4)
    const int br = tid >> 3, bc = (tid & 7) * 16;
    const int bswz = bc ^ ((br & 7) << 4);               // r&7 == br&7 (p*32 % 8 == 0)
    const unsigned short* bSrc = WtG + (size_t)br * H_ + (bswz >> 1);
    const int bDstOff = br * 64 + (bc >> 1);             // shorts; + p*2048

    // compute-side fragment offsets
    const int aOff = (wm * 16 + lr) * BKP + q * 8;       // shorts
    int bOff[5];
#pragma unroll
    for (int tt = 0; tt < 5; ++tt) {
        const int row = wn * 80 + tt * 16 + lr;
        bOff[tt] = row * 128 + ((q * 16) ^ ((row & 7) << 4));   // bytes; ^ (kk*2) per k-substep
    }

    floatx4 acc[5];
#pragma unroll
    for (int tt = 0; tt < 5; ++tt) acc[tt] = (floatx4){0.f, 0.f, 0.f, 0.f};

    // prologue: stage chunk 0 into buffer 0
    {
        float4 v0 = *(const float4*)(aSrc);
        float4 v1 = *(const float4*)(aSrc + 16 * H_);
#pragma unroll
        for (int p = 0; p < 5; ++p)
            gload_lds16(bSrc + (size_t)p * 32 * H_, &Bsm[0][p * 2048 + bDstOff]);
        u16x4 u0 = { f2bf(v0.x), f2bf(v0.y), f2bf(v0.z), f2bf(v0.w) };
        u16x4 u1 = { f2bf(v1.x), f2bf(v1.y), f2bf(v1.z), f2bf(v1.w) };
        *(u16x4*)aD0 = u0;
        *(u16x4*)(aD0 + 16 * BKP) = u1;
    }
    __syncthreads();   // drains vmcnt(0)+lgkmcnt(0): buffer 0 ready

    int cur = 0;
    for (int t = 0; t < NCHUNK; ++t) {
        const int nk = (t + 1) * BK;
        float4 v0, v1;
        if (t < NCHUNK - 1) {
            // issue next chunk's loads BEFORE compute (overlap)
            v0 = *(const float4*)(aSrc + nk);
            v1 = *(const float4*)(aSrc + 16 * H_ + nk);
            unsigned short* bN = &Bsm[cur ^ 1][0];
#pragma unroll
            for (int p = 0; p < 5; ++p)
                gload_lds16(bSrc + (size_t)p * 32 * H_ + nk, bN + p * 2048 + bDstOff);
        }
        // compute chunk t from buffer cur
        const unsigned short* Ac = &Asm[cur][0];
        const char* Bc = (const char*)&Bsm[cur][0];
#pragma unroll
        for (int kk = 0; kk < BK; kk += 32) {
            short8 afr = *(const short8*)&Ac[aOff + kk];
#pragma unroll
            for (int tt = 0; tt < 5; ++tt) {
                short8 bfr = *(const short8*)(Bc + (bOff[tt] ^ (kk << 1)));
                acc[tt] = __builtin_amdgcn_mfma_f32_16x16x32_bf16(afr, bfr, acc[tt], 0, 0, 0);
            }
        }
        if (t < NCHUNK - 1) {
            // A cvt + LDS write into next buffer (A-load latency hid under MFMAs)
            unsigned short* aDN = cur ? aD0 : aD1;
            u16x4 u0 = { f2bf(v0.x), f2bf(v0.y), f2bf(v0.z), f2bf(v0.w) };
            u16x4 u1 = { f2bf(v1.x), f2bf(v1.y), f2bf(v1.z), f2bf(v1.w) };
            *(u16x4*)aDN = u0;
            *(u16x4*)(aDN + 16 * BKP) = u1;
            __syncthreads();   // drains B gload_lds (flew during compute) + A writes
            cur ^= 1;
        }
    }

    // epilogue: logits -> BCE * mask -> sum
    float lsum = 0.0f;
#pragma unroll
    for (int tt = 0; tt < 5; ++tt) {
        const int col = wn * 80 + tt * 16 + lr;
        if (col < NVALID) {
            const float rb = rowBias[b * NPAD + col];
#pragma unroll
            for (int i = 0; i < 4; ++i) {
                const int row = gm0 + wm * 16 + q * 4 + i;
                const float l = acc[tt][i] + rb;
                float tgt;
                if (col < 64)        tgt = oh[(size_t)row * R_ + col];
                else if (col < 128)  tgt = ot[(size_t)row * R_ + (col - 64)];
                else if (col == 128) tgt = ash[row];
                else                 tgt = ast[row];
                const float mk = masks[row];
                const float bce = fmaxf(l, 0.0f) - l * tgt + log1pf(__expf(-fabsf(l)));
                lsum += bce * mk;
            }
        }
    }
    for (int o = 32; o > 0; o >>= 1) lsum += __shfl_down(lsum, o, 64);
    if (lane == 0) rbuf[wave] = lsum;
    __syncthreads();
    if (tid == 0) {
        atomicAdd(&accum[0], rbuf[0] + rbuf[1] + rbuf[2] + rbuf[3]);
        __threadfence();
        const unsigned int prev = atomicAdd((unsigned int*)(accum + 2), 1u);
        if (prev == gridDim.x - 1) {   // last block finalizes
            const float s = atomicAdd(&accum[0], 0.0f);
            const float m = atomicAdd(&accum[1], 0.0f);
            out[0] = s / m;
        }
    }
}

extern "C" void kernel_launch(void* const* d_in, const int* in_sizes, int n_in,
                              void* d_out, int out_size, void* d_ws, size_t ws_size,
                              hipStream_t stream) {
    const float* ctx   = (const float*)d_in[0];
    const float* masks = (const float*)d_in[1];
    const float* ash   = (const float*)d_in[2];
    const float* ast   = (const float*)d_in[3];
    const float* sh    = (const float*)d_in[4];
    const float* st    = (const float*)d_in[5];
    const float* oh    = (const float*)d_in[6];
    const float* ot    = (const float*)d_in[7];
    const float* Ws_h  = (const float*)d_in[8];
    const float* bs_h  = (const float*)d_in[9];
    const float* Ws_t  = (const float*)d_in[10];
    const float* bs_t  = (const float*)d_in[11];
    const float* Wo_h  = (const float*)d_in[12];
    const float* bo_h  = (const float*)d_in[13];
    const float* Wo_t  = (const float*)d_in[14];
    const float* bo_t  = (const float*)d_in[15];
    float* out = (float*)d_out;

    char* ws = (char*)d_ws;
    float* accum   = (float*)(ws + 0);                 // [0]=loss, [1]=msum, [2]=counter
    float* rowBias = (float*)(ws + 256);               // [32][160] fp32
    unsigned short* WtG = (unsigned short*)(ws + 256 + 32 * NPAD * 4); // [160][1024] bf16

    hipMemsetAsync(accum, 0, 12, stream);
    aux_kernel<<<NPAD + B_, 256, 0, stream>>>(ctx, sh, st, masks, Wo_h, Wo_t,
                                              Ws_h, Ws_t, bo_h, bo_t, bs_h, bs_t,
                                              WtG, rowBias, accum);
    main_kernel<<<M_ / MT, 256, 0, stream>>>(ctx, WtG, rowBias, masks,
                                             ash, ast, oh, ot, accum, out);
}

// Round 3
// 167.875 us; speedup vs baseline: 1.3718x; 1.2629x over previous
//
#include <hip/hip_runtime.h>

// CASREL loss, B=32,S=512,H=1024,R=64 -> scalar fp32 loss.
// v4: main_kernel unchanged from v3 (double-buffered global_load_lds pipeline,
// verified). aux_kernel rewritten: LDS-tiled coalesced transpose for WtG
// (was stride-256B scalar reads) and 8-way-k-split float4 rowBias dot
// (was a 512-trip latency-serial loop = 43us).

#define B_  32
#define S_  512
#define H_  1024
#define R_  64
#define M_  (B_ * S_)      // 16384 rows
#define NPAD 160           // 130 valid cols padded
#define NVALID 130
#define BK 64
#define BKP 72             // A LDS pad (2-way conflicts = free)
#define MT 32              // rows per block
#define NCHUNK (H_ / BK)   // 16
#define TBLK 20            // transpose blocks (5 n-tiles x 4 k-tiles)

typedef __attribute__((ext_vector_type(4))) float  floatx4;
typedef __attribute__((ext_vector_type(8))) short  short8;     // 8 bf16
typedef __attribute__((ext_vector_type(4))) unsigned short u16x4;
typedef __attribute__((ext_vector_type(8))) unsigned short u16x8;

__device__ __forceinline__ unsigned short f2bf(float f) {
    unsigned int u = __float_as_uint(f);
    u = (u + 0x7FFFu + ((u >> 16) & 1u)) >> 16;   // RNE
    return (unsigned short)u;
}

__device__ __forceinline__ void gload_lds16(const unsigned short* g, unsigned short* l) {
    __builtin_amdgcn_global_load_lds(
        (const __attribute__((address_space(1))) unsigned int*)g,
        (__attribute__((address_space(3))) unsigned int*)l, 16, 0, 0);
}

// ---- K1 (merged): blocks [0,TBLK) transpose WtG; blocks [TBLK,TBLK+B_) subj ----
__global__ __launch_bounds__(256) void aux_kernel(
        const float* __restrict__ ctx, const float* __restrict__ head,
        const float* __restrict__ tail, const float* __restrict__ masks,
        const float* __restrict__ Wo_h, const float* __restrict__ Wo_t,
        const float* __restrict__ Ws_h, const float* __restrict__ Ws_t,
        const float* __restrict__ bo_h, const float* __restrict__ bo_t,
        const float* __restrict__ bs_h, const float* __restrict__ bs_t,
        unsigned short* __restrict__ WtG, float* __restrict__ rowBias,
        float* __restrict__ accum) {
    const int tid = threadIdx.x;
    __shared__ float tr[32][257];      // transpose tile (pad 257: conflict-free)
    __shared__ float subj[H_];
    __shared__ float partS[4][256];
    __shared__ int cnt;
    __shared__ int   sidx[8];
    __shared__ float sw[8];

    if (blockIdx.x < TBLK) {
        const int kt = blockIdx.x / 5, nt = blockIdx.x % 5;
        const int k0 = kt * 256, n0 = nt * 32;
        if (n0 < 128) {
            // coalesced read of W[k0:k0+256][n0:n0+32] -> LDS transposed
            const float* src = (n0 < 64) ? Wo_h : Wo_t;
            const int cb = n0 & 63;
            const int nn = tid & 31, kk = tid >> 5;   // 8 k-rows per pass
#pragma unroll
            for (int i = 0; i < 32; ++i) {
                const int k = k0 + i * 8 + kk;
                tr[nn][i * 8 + kk] = src[(size_t)k * R_ + cb + nn];
            }
            __syncthreads();
            // coalesced write: k-contiguous 16B chunks of WtG
#pragma unroll
            for (int p = 0; p < 4; ++p) {
                const int chunk = p * 256 + tid;
                const int n = chunk >> 5;             // 0..31
                const int kc = (chunk & 31) * 8;
                u16x8 v;
#pragma unroll
                for (int j = 0; j < 8; ++j) v[j] = f2bf(tr[n][kc + j]);
                *(u16x8*)(WtG + (size_t)(n0 + n) * H_ + k0 + kc) = v;
            }
        } else {
            // special tile: row 128 = Ws_h, 129 = Ws_t, 130..159 = 0
#pragma unroll
            for (int p = 0; p < 4; ++p) {
                const int chunk = p * 256 + tid;
                const int n = 128 + (chunk >> 5);
                const int kc = (chunk & 31) * 8;
                u16x8 v;
#pragma unroll
                for (int j = 0; j < 8; ++j) {
                    float f = (n == 128) ? Ws_h[k0 + kc + j]
                            : (n == 129) ? Ws_t[k0 + kc + j] : 0.0f;
                    v[j] = f2bf(f);
                }
                *(u16x8*)(WtG + (size_t)n * H_ + k0 + kc) = v;
            }
        }
        return;
    }

    const int b = blockIdx.x - TBLK;
    if (tid == 0) cnt = 0;
    __syncthreads();
    float msk = 0.0f;
    for (int s = tid; s < S_; s += 256) {
        float w = 0.5f * (head[b * S_ + s] + tail[b * S_ + s]);
        if (w != 0.0f) {
            int i = atomicAdd(&cnt, 1);
            if (i < 8) { sidx[i] = s; sw[i] = w; }
        }
        msk += masks[b * S_ + s];
    }
    for (int o = 32; o > 0; o >>= 1) msk += __shfl_down(msk, o, 64);
    if ((tid & 63) == 0) atomicAdd(&accum[1], msk);
    __syncthreads();
    const int nnz = cnt < 8 ? cnt : 8;
    for (int h = tid; h < H_; h += 256) {
        float a = 0.0f;
        for (int i = 0; i < nnz; i++)
            a += sw[i] * ctx[((size_t)b * S_ + sidx[i]) * H_ + h];
        subj[h] = a;
    }
    __syncthreads();
    // rowBias dot: thread = (c-group of 4, k-slice of 128); float4 W loads
    {
        const int cg = tid & 31;          // c4 = cg*4 in 0..124
        const int ks = tid >> 5;          // 0..7
        const int c4 = cg * 4;
        const float* W = (c4 < 64) ? Wo_h : Wo_t;
        const int cc = c4 & 63;
        const int kk0 = ks * 128;
        float ax = 0.f, ay = 0.f, az = 0.f, aw = 0.f;
#pragma unroll 4
        for (int k = kk0; k < kk0 + 128; ++k) {
            const float4 w = *(const float4*)(W + (size_t)k * R_ + cc);
            const float sv = subj[k];
            ax += sv * w.x; ay += sv * w.y; az += sv * w.z; aw += sv * w.w;
        }
        partS[0][tid] = ax; partS[1][tid] = ay;
        partS[2][tid] = az; partS[3][tid] = aw;
    }
    __syncthreads();
    if (tid < NPAD) {
        float bias = tid < 64  ? bo_h[tid]
                   : tid < 128 ? bo_t[tid - 64]
                   : tid == 128 ? bs_h[0]
                   : tid == 129 ? bs_t[0] : 0.0f;
        float a2 = 0.0f;
        if (tid < 128) {
            const int g = tid >> 2, j = tid & 3;
#pragma unroll
            for (int s = 0; s < 8; ++s) a2 += partS[j][s * 32 + g];
        }
        rowBias[b * NPAD + tid] = bias + a2;
    }
}

// ---- K2: double-buffered pipelined GEMM + BCE + masked reduction + finalize ----
__global__ __launch_bounds__(256, 2) void main_kernel(
        const float* __restrict__ ctx, const unsigned short* __restrict__ WtG,
        const float* __restrict__ rowBias, const float* __restrict__ masks,
        const float* __restrict__ ash, const float* __restrict__ ast,
        const float* __restrict__ oh, const float* __restrict__ ot,
        float* __restrict__ accum, float* __restrict__ out) {
    __shared__ __align__(16) unsigned short Asm[2][MT * BKP];    // 9.2 KB
    __shared__ __align__(16) unsigned short Bsm[2][NPAD * BK];   // 41 KB
    __shared__ float rbuf[4];

    const int tid  = threadIdx.x;
    const int gm0  = blockIdx.x * MT;
    const int b    = gm0 >> 9;
    const int wave = tid >> 6, lane = tid & 63;
    const int wm = wave & 1;            // row half (16 rows)
    const int wn = wave >> 1;           // col half (80 cols = 5 tiles)
    const int lr = lane & 15, q = lane >> 4;   // q in 0..3

    // A staging map: rows ar, ar+16; 16B (4 floats) per thread per row
    const int ar = tid >> 4, af = tid & 15;
    const float* aSrc = ctx + (size_t)(gm0 + ar) * H_ + af * 4;
    unsigned short* aD0 = &Asm[0][ar * BKP + af * 4];
    unsigned short* aD1 = &Asm[1][ar * BKP + af * 4];

    // B staging map (global_load_lds, linear LDS dest, source XOR-swizzled):
    // pass p: r = p*32 + (tid>>3), c = (tid&7)*16 bytes; src byte = c ^ ((r&7)<<4)
    const int br = tid >> 3, bc = (tid & 7) * 16;
    const int bswz = bc ^ ((br & 7) << 4);               // r&7 == br&7 (p*32 % 8 == 0)
    const unsigned short* bSrc = WtG + (size_t)br * H_ + (bswz >> 1);
    const int bDstOff = br * 64 + (bc >> 1);             // shorts; + p*2048

    // compute-side fragment offsets
    const int aOff = (wm * 16 + lr) * BKP + q * 8;       // shorts
    int bOff[5];
#pragma unroll
    for (int tt = 0; tt < 5; ++tt) {
        const int row = wn * 80 + tt * 16 + lr;
        bOff[tt] = row * 128 + ((q * 16) ^ ((row & 7) << 4));   // bytes; ^ (kk*2) per k-substep
    }

    floatx4 acc[5];
#pragma unroll
    for (int tt = 0; tt < 5; ++tt) acc[tt] = (floatx4){0.f, 0.f, 0.f, 0.f};

    // prologue: stage chunk 0 into buffer 0
    {
        float4 v0 = *(const float4*)(aSrc);
        float4 v1 = *(const float4*)(aSrc + 16 * H_);
#pragma unroll
        for (int p = 0; p < 5; ++p)
            gload_lds16(bSrc + (size_t)p * 32 * H_, &Bsm[0][p * 2048 + bDstOff]);
        u16x4 u0 = { f2bf(v0.x), f2bf(v0.y), f2bf(v0.z), f2bf(v0.w) };
        u16x4 u1 = { f2bf(v1.x), f2bf(v1.y), f2bf(v1.z), f2bf(v1.w) };
        *(u16x4*)aD0 = u0;
        *(u16x4*)(aD0 + 16 * BKP) = u1;
    }
    __syncthreads();   // drains vmcnt(0)+lgkmcnt(0): buffer 0 ready

    int cur = 0;
    for (int t = 0; t < NCHUNK; ++t) {
        const int nk = (t + 1) * BK;
        float4 v0, v1;
        if (t < NCHUNK - 1) {
            // issue next chunk's loads BEFORE compute (overlap)
            v0 = *(const float4*)(aSrc + nk);
            v1 = *(const float4*)(aSrc + 16 * H_ + nk);
            unsigned short* bN = &Bsm[cur ^ 1][0];
#pragma unroll
            for (int p = 0; p < 5; ++p)
                gload_lds16(bSrc + (size_t)p * 32 * H_ + nk, bN + p * 2048 + bDstOff);
        }
        // compute chunk t from buffer cur
        const unsigned short* Ac = &Asm[cur][0];
        const char* Bc = (const char*)&Bsm[cur][0];
#pragma unroll
        for (int kk = 0; kk < BK; kk += 32) {
            short8 afr = *(const short8*)&Ac[aOff + kk];
#pragma unroll
            for (int tt = 0; tt < 5; ++tt) {
                short8 bfr = *(const short8*)(Bc + (bOff[tt] ^ (kk << 1)));
                acc[tt] = __builtin_amdgcn_mfma_f32_16x16x32_bf16(afr, bfr, acc[tt], 0, 0, 0);
            }
        }
        if (t < NCHUNK - 1) {
            // A cvt + LDS write into next buffer (A-load latency hid under MFMAs)
            unsigned short* aDN = cur ? aD0 : aD1;
            u16x4 u0 = { f2bf(v0.x), f2bf(v0.y), f2bf(v0.z), f2bf(v0.w) };
            u16x4 u1 = { f2bf(v1.x), f2bf(v1.y), f2bf(v1.z), f2bf(v1.w) };
            *(u16x4*)aDN = u0;
            *(u16x4*)(aDN + 16 * BKP) = u1;
            __syncthreads();   // drains B gload_lds (flew during compute) + A writes
            cur ^= 1;
        }
    }

    // epilogue: logits -> BCE * mask -> sum
    float lsum = 0.0f;
#pragma unroll
    for (int tt = 0; tt < 5; ++tt) {
        const int col = wn * 80 + tt * 16 + lr;
        if (col < NVALID) {
            const float rb = rowBias[b * NPAD + col];
#pragma unroll
            for (int i = 0; i < 4; ++i) {
                const int row = gm0 + wm * 16 + q * 4 + i;
                const float l = acc[tt][i] + rb;
                float tgt;
                if (col < 64)        tgt = oh[(size_t)row * R_ + col];
                else if (col < 128)  tgt = ot[(size_t)row * R_ + (col - 64)];
                else if (col == 128) tgt = ash[row];
                else                 tgt = ast[row];
                const float mk = masks[row];
                const float bce = fmaxf(l, 0.0f) - l * tgt + log1pf(__expf(-fabsf(l)));
                lsum += bce * mk;
            }
        }
    }
    for (int o = 32; o > 0; o >>= 1) lsum += __shfl_down(lsum, o, 64);
    if (lane == 0) rbuf[wave] = lsum;
    __syncthreads();
    if (tid == 0) {
        atomicAdd(&accum[0], rbuf[0] + rbuf[1] + rbuf[2] + rbuf[3]);
        __threadfence();
        const unsigned int prev = atomicAdd((unsigned int*)(accum + 2), 1u);
        if (prev == gridDim.x - 1) {   // last block finalizes
            const float s = atomicAdd(&accum[0], 0.0f);
            const float m = atomicAdd(&accum[1], 0.0f);
            out[0] = s / m;
        }
    }
}

extern "C" void kernel_launch(void* const* d_in, const int* in_sizes, int n_in,
                              void* d_out, int out_size, void* d_ws, size_t ws_size,
                              hipStream_t stream) {
    const float* ctx   = (const float*)d_in[0];
    const float* masks = (const float*)d_in[1];
    const float* ash   = (const float*)d_in[2];
    const float* ast   = (const float*)d_in[3];
    const float* sh    = (const float*)d_in[4];
    const float* st    = (const float*)d_in[5];
    const float* oh    = (const float*)d_in[6];
    const float* ot    = (const float*)d_in[7];
    const float* Ws_h  = (const float*)d_in[8];
    const float* bs_h  = (const float*)d_in[9];
    const float* Ws_t  = (const float*)d_in[10];
    const float* bs_t  = (const float*)d_in[11];
    const float* Wo_h  = (const float*)d_in[12];
    const float* bo_h  = (const float*)d_in[13];
    const float* Wo_t  = (const float*)d_in[14];
    const float* bo_t  = (const float*)d_in[15];
    float* out = (float*)d_out;

    char* ws = (char*)d_ws;
    float* accum   = (float*)(ws + 0);                 // [0]=loss, [1]=msum, [2]=counter
    float* rowBias = (float*)(ws + 256);               // [32][160] fp32
    unsigned short* WtG = (unsigned short*)(ws + 256 + 32 * NPAD * 4); // [160][1024] bf16

    hipMemsetAsync(accum, 0, 12, stream);
    aux_kernel<<<TBLK + B_, 256, 0, stream>>>(ctx, sh, st, masks, Wo_h, Wo_t,
                                              Ws_h, Ws_t, bo_h, bo_t, bs_h, bs_t,
                                              WtG, rowBias, accum);
    main_kernel<<<M_ / MT, 256, 0, stream>>>(ctx, WtG, rowBias, masks,
                                             ash, ast, oh, ot, accum, out);
}

// Round 4
// 167.411 us; speedup vs baseline: 1.3756x; 1.0028x over previous
//
#include <hip/hip_runtime.h>

// CASREL loss, B=32,S=512,H=1024,R=64 -> scalar fp32 loss.
// v5: occupancy fix. main_kernel goes 4 waves -> 10 waves/block (640 thr),
// each wave owns 16 rows x 32 cols (2 frags). Grid 512 = 2 blocks/CU, now
// 20 waves/CU (62% occ) instead of 8 (13.7%). Data paths (A reg-stage+cvt,
// B global_load_lds with source-XOR swizzle), K order, and per-output MFMA
// sequence identical to verified v4. aux_kernel unchanged from v4.

#define B_  32
#define S_  512
#define H_  1024
#define R_  64
#define M_  (B_ * S_)      // 16384 rows
#define NPAD 160           // 130 valid cols padded
#define NVALID 130
#define BK 64
#define BKP 72             // A LDS pad (2-way conflicts = free)
#define MT 32              // rows per block
#define NCHUNK (H_ / BK)   // 16
#define TBLK 20            // transpose blocks (5 n-tiles x 4 k-tiles)
#define NTHR 640           // 10 waves

typedef __attribute__((ext_vector_type(4))) float  floatx4;
typedef __attribute__((ext_vector_type(8))) short  short8;     // 8 bf16
typedef __attribute__((ext_vector_type(4))) unsigned short u16x4;
typedef __attribute__((ext_vector_type(8))) unsigned short u16x8;

__device__ __forceinline__ unsigned short f2bf(float f) {
    unsigned int u = __float_as_uint(f);
    u = (u + 0x7FFFu + ((u >> 16) & 1u)) >> 16;   // RNE
    return (unsigned short)u;
}

__device__ __forceinline__ void gload_lds16(const unsigned short* g, unsigned short* l) {
    __builtin_amdgcn_global_load_lds(
        (const __attribute__((address_space(1))) unsigned int*)g,
        (__attribute__((address_space(3))) unsigned int*)l, 16, 0, 0);
}

// ---- K1 (merged): blocks [0,TBLK) transpose WtG; blocks [TBLK,TBLK+B_) subj ----
__global__ __launch_bounds__(256) void aux_kernel(
        const float* __restrict__ ctx, const float* __restrict__ head,
        const float* __restrict__ tail, const float* __restrict__ masks,
        const float* __restrict__ Wo_h, const float* __restrict__ Wo_t,
        const float* __restrict__ Ws_h, const float* __restrict__ Ws_t,
        const float* __restrict__ bo_h, const float* __restrict__ bo_t,
        const float* __restrict__ bs_h, const float* __restrict__ bs_t,
        unsigned short* __restrict__ WtG, float* __restrict__ rowBias,
        float* __restrict__ accum) {
    const int tid = threadIdx.x;
    __shared__ float tr[32][257];      // transpose tile (pad 257: conflict-free)
    __shared__ float subj[H_];
    __shared__ float partS[4][256];
    __shared__ int cnt;
    __shared__ int   sidx[8];
    __shared__ float sw[8];

    if (blockIdx.x < TBLK) {
        const int kt = blockIdx.x / 5, nt = blockIdx.x % 5;
        const int k0 = kt * 256, n0 = nt * 32;
        if (n0 < 128) {
            // coalesced read of W[k0:k0+256][n0:n0+32] -> LDS transposed
            const float* src = (n0 < 64) ? Wo_h : Wo_t;
            const int cb = n0 & 63;
            const int nn = tid & 31, kk = tid >> 5;   // 8 k-rows per pass
#pragma unroll
            for (int i = 0; i < 32; ++i) {
                const int k = k0 + i * 8 + kk;
                tr[nn][i * 8 + kk] = src[(size_t)k * R_ + cb + nn];
            }
            __syncthreads();
            // coalesced write: k-contiguous 16B chunks of WtG
#pragma unroll
            for (int p = 0; p < 4; ++p) {
                const int chunk = p * 256 + tid;
                const int n = chunk >> 5;             // 0..31
                const int kc = (chunk & 31) * 8;
                u16x8 v;
#pragma unroll
                for (int j = 0; j < 8; ++j) v[j] = f2bf(tr[n][kc + j]);
                *(u16x8*)(WtG + (size_t)(n0 + n) * H_ + k0 + kc) = v;
            }
        } else {
            // special tile: row 128 = Ws_h, 129 = Ws_t, 130..159 = 0
#pragma unroll
            for (int p = 0; p < 4; ++p) {
                const int chunk = p * 256 + tid;
                const int n = 128 + (chunk >> 5);
                const int kc = (chunk & 31) * 8;
                u16x8 v;
#pragma unroll
                for (int j = 0; j < 8; ++j) {
                    float f = (n == 128) ? Ws_h[k0 + kc + j]
                            : (n == 129) ? Ws_t[k0 + kc + j] : 0.0f;
                    v[j] = f2bf(f);
                }
                *(u16x8*)(WtG + (size_t)n * H_ + k0 + kc) = v;
            }
        }
        return;
    }

    const int b = blockIdx.x - TBLK;
    if (tid == 0) cnt = 0;
    __syncthreads();
    float msk = 0.0f;
    for (int s = tid; s < S_; s += 256) {
        float w = 0.5f * (head[b * S_ + s] + tail[b * S_ + s]);
        if (w != 0.0f) {
            int i = atomicAdd(&cnt, 1);
            if (i < 8) { sidx[i] = s; sw[i] = w; }
        }
        msk += masks[b * S_ + s];
    }
    for (int o = 32; o > 0; o >>= 1) msk += __shfl_down(msk, o, 64);
    if ((tid & 63) == 0) atomicAdd(&accum[1], msk);
    __syncthreads();
    const int nnz = cnt < 8 ? cnt : 8;
    for (int h = tid; h < H_; h += 256) {
        float a = 0.0f;
        for (int i = 0; i < nnz; i++)
            a += sw[i] * ctx[((size_t)b * S_ + sidx[i]) * H_ + h];
        subj[h] = a;
    }
    __syncthreads();
    // rowBias dot: thread = (c-group of 4, k-slice of 128); float4 W loads
    {
        const int cg = tid & 31;          // c4 = cg*4 in 0..124
        const int ks = tid >> 5;          // 0..7
        const int c4 = cg * 4;
        const float* W = (c4 < 64) ? Wo_h : Wo_t;
        const int cc = c4 & 63;
        const int kk0 = ks * 128;
        float ax = 0.f, ay = 0.f, az = 0.f, aw = 0.f;
#pragma unroll 4
        for (int k = kk0; k < kk0 + 128; ++k) {
            const float4 w = *(const float4*)(W + (size_t)k * R_ + cc);
            const float sv = subj[k];
            ax += sv * w.x; ay += sv * w.y; az += sv * w.z; aw += sv * w.w;
        }
        partS[0][tid] = ax; partS[1][tid] = ay;
        partS[2][tid] = az; partS[3][tid] = aw;
    }
    __syncthreads();
    if (tid < NPAD) {
        float bias = tid < 64  ? bo_h[tid]
                   : tid < 128 ? bo_t[tid - 64]
                   : tid == 128 ? bs_h[0]
                   : tid == 129 ? bs_t[0] : 0.0f;
        float a2 = 0.0f;
        if (tid < 128) {
            const int g = tid >> 2, j = tid & 3;
#pragma unroll
            for (int s = 0; s < 8; ++s) a2 += partS[j][s * 32 + g];
        }
        rowBias[b * NPAD + tid] = bias + a2;
    }
}

// ---- K2: 10-wave double-buffered GEMM + BCE + masked reduction + finalize ----
__global__ __launch_bounds__(NTHR, 4) void main_kernel(
        const float* __restrict__ ctx, const unsigned short* __restrict__ WtG,
        const float* __restrict__ rowBias, const float* __restrict__ masks,
        const float* __restrict__ ash, const float* __restrict__ ast,
        const float* __restrict__ oh, const float* __restrict__ ot,
        float* __restrict__ accum, float* __restrict__ out) {
    __shared__ __align__(16) unsigned short Asm[2][MT * BKP];    // 9.2 KB
    __shared__ __align__(16) unsigned short Bsm[2][NPAD * BK];   // 41 KB
    __shared__ float rbuf[10];

    const int tid  = threadIdx.x;
    const int gm0  = blockIdx.x * MT;
    const int b    = gm0 >> 9;
    const int wave = tid >> 6, lane = tid & 63;
    const int wm = wave & 1;            // row half (16 rows)
    const int wn = wave >> 1;           // col group of 32 (2 tiles), 0..4
    const int lr = lane & 15, q = lane >> 4;   // q in 0..3

    // A staging map: threads 0..511 stage one row each; 16B (4 floats)
    const int ar = tid >> 4, af = tid & 15;      // ar 0..39 (use <32)
    const bool aAct = tid < 512;
    const float* aSrc = ctx + (size_t)(gm0 + ar) * H_ + af * 4;
    unsigned short* aD0 = &Asm[0][ar * BKP + af * 4];
    unsigned short* aD1 = &Asm[1][ar * BKP + af * 4];

    // B staging map (global_load_lds, linear LDS dest, source XOR-swizzled):
    // pass p: r = p*80 + (tid>>3), c = (tid&7)*16 bytes; src byte = c ^ ((r&7)<<4)
    const int br = tid >> 3, bc = (tid & 7) * 16;    // br 0..79
    const int bswz = bc ^ ((br & 7) << 4);           // (p*80)&7==0 -> same all passes
    const unsigned short* bSrc = WtG + (size_t)br * H_ + (bswz >> 1);
    const int bDstOff = br * 64 + (bc >> 1);         // shorts; + p*5120

    // compute-side fragment offsets
    const int aOff = (wm * 16 + lr) * BKP + q * 8;   // shorts
    int bOff[2];
#pragma unroll
    for (int tt = 0; tt < 2; ++tt) {
        const int row = wn * 32 + tt * 16 + lr;
        bOff[tt] = row * 128 + ((q * 16) ^ ((row & 7) << 4));   // bytes; ^ (kk*2) per substep
    }

    floatx4 acc[2];
#pragma unroll
    for (int tt = 0; tt < 2; ++tt) acc[tt] = (floatx4){0.f, 0.f, 0.f, 0.f};

    // prologue: stage chunk 0 into buffer 0
    {
        float4 v0;
        if (aAct) v0 = *(const float4*)(aSrc);
#pragma unroll
        for (int p = 0; p < 2; ++p)
            gload_lds16(bSrc + (size_t)p * 80 * H_, &Bsm[0][p * 5120 + bDstOff]);
        if (aAct) {
            u16x4 u0 = { f2bf(v0.x), f2bf(v0.y), f2bf(v0.z), f2bf(v0.w) };
            *(u16x4*)aD0 = u0;
        }
    }
    __syncthreads();   // buffer 0 ready

    int cur = 0;
    for (int t = 0; t < NCHUNK; ++t) {
        const int nk = (t + 1) * BK;
        float4 v0;
        if (t < NCHUNK - 1) {
            // issue next chunk's loads BEFORE compute (overlap)
            if (aAct) v0 = *(const float4*)(aSrc + nk);
            unsigned short* bN = &Bsm[cur ^ 1][0];
#pragma unroll
            for (int p = 0; p < 2; ++p)
                gload_lds16(bSrc + (size_t)p * 80 * H_ + nk, bN + p * 5120 + bDstOff);
        }
        // compute chunk t from buffer cur
        const unsigned short* Ac = &Asm[cur][0];
        const char* Bc = (const char*)&Bsm[cur][0];
#pragma unroll
        for (int kk = 0; kk < BK; kk += 32) {
            short8 afr = *(const short8*)&Ac[aOff + kk];
#pragma unroll
            for (int tt = 0; tt < 2; ++tt) {
                short8 bfr = *(const short8*)(Bc + (bOff[tt] ^ (kk << 1)));
                acc[tt] = __builtin_amdgcn_mfma_f32_16x16x32_bf16(afr, bfr, acc[tt], 0, 0, 0);
            }
        }
        if (t < NCHUNK - 1) {
            if (aAct) {
                u16x4 u0 = { f2bf(v0.x), f2bf(v0.y), f2bf(v0.z), f2bf(v0.w) };
                *(u16x4*)(cur ? aD0 : aD1) = u0;
            }
            __syncthreads();   // drains B gload_lds (flew during compute) + A writes
            cur ^= 1;
        }
    }

    // epilogue: logits -> BCE * mask -> sum
    float lsum = 0.0f;
#pragma unroll
    for (int tt = 0; tt < 2; ++tt) {
        const int col = wn * 32 + tt * 16 + lr;
        if (col < NVALID) {
            const float rb = rowBias[b * NPAD + col];
#pragma unroll
            for (int i = 0; i < 4; ++i) {
                const int row = gm0 + wm * 16 + q * 4 + i;
                const float l = acc[tt][i] + rb;
                float tgt;
                if (col < 64)        tgt = oh[(size_t)row * R_ + col];
                else if (col < 128)  tgt = ot[(size_t)row * R_ + (col - 64)];
                else if (col == 128) tgt = ash[row];
                else                 tgt = ast[row];
                const float mk = masks[row];
                const float bce = fmaxf(l, 0.0f) - l * tgt + log1pf(__expf(-fabsf(l)));
                lsum += bce * mk;
            }
        }
    }
    for (int o = 32; o > 0; o >>= 1) lsum += __shfl_down(lsum, o, 64);
    if (lane == 0) rbuf[wave] = lsum;
    __syncthreads();
    if (tid == 0) {
        float s0 = 0.0f;
#pragma unroll
        for (int w = 0; w < 10; ++w) s0 += rbuf[w];
        atomicAdd(&accum[0], s0);
        __threadfence();
        const unsigned int prev = atomicAdd((unsigned int*)(accum + 2), 1u);
        if (prev == gridDim.x - 1) {   // last block finalizes
            const float s = atomicAdd(&accum[0], 0.0f);
            const float m = atomicAdd(&accum[1], 0.0f);
            out[0] = s / m;
        }
    }
}

extern "C" void kernel_launch(void* const* d_in, const int* in_sizes, int n_in,
                              void* d_out, int out_size, void* d_ws, size_t ws_size,
                              hipStream_t stream) {
    const float* ctx   = (const float*)d_in[0];
    const float* masks = (const float*)d_in[1];
    const float* ash   = (const float*)d_in[2];
    const float* ast   = (const float*)d_in[3];
    const float* sh    = (const float*)d_in[4];
    const float* st    = (const float*)d_in[5];
    const float* oh    = (const float*)d_in[6];
    const float* ot    = (const float*)d_in[7];
    const float* Ws_h  = (const float*)d_in[8];
    const float* bs_h  = (const float*)d_in[9];
    const float* Ws_t  = (const float*)d_in[10];
    const float* bs_t  = (const float*)d_in[11];
    const float* Wo_h  = (const float*)d_in[12];
    const float* bo_h  = (const float*)d_in[13];
    const float* Wo_t  = (const float*)d_in[14];
    const float* bo_t  = (const float*)d_in[15];
    float* out = (float*)d_out;

    char* ws = (char*)d_ws;
    float* accum   = (float*)(ws + 0);                 // [0]=loss, [1]=msum, [2]=counter
    float* rowBias = (float*)(ws + 256);               // [32][160] fp32
    unsigned short* WtG = (unsigned short*)(ws + 256 + 32 * NPAD * 4); // [160][1024] bf16

    hipMemsetAsync(accum, 0, 12, stream);
    aux_kernel<<<TBLK + B_, 256, 0, stream>>>(ctx, sh, st, masks, Wo_h, Wo_t,
                                              Ws_h, Ws_t, bo_h, bo_t, bs_h, bs_t,
                                              WtG, rowBias, accum);
    main_kernel<<<M_ / MT, NTHR, 0, stream>>>(ctx, WtG, rowBias, masks,
                                              ash, ast, oh, ot, accum, out);
}